// Round 4
// baseline (474.091 us; speedup 1.0000x reference)
//
#include <hip/hip_runtime.h>
#include <hip/hip_bf16.h>

#define B_ 2
#define T_ 2048
#define C_ 1024
#define H_ 16
#define HD_ 64
#define O_ 1152   // C + 2*HD

typedef __attribute__((ext_vector_type(8))) short bf16x8;
typedef __attribute__((ext_vector_type(4))) float f32x4;

__device__ inline short f2bf(float f) {
    union { float f; unsigned u; } v; v.f = f;
    unsigned r = v.u + 0x7FFFu + ((v.u >> 16) & 1u);
    return (short)(r >> 16);
}

__device__ inline bf16x8 loadAB(const float* p) {
    f32x4 x0 = *(const f32x4*)p;
    f32x4 x1 = *(const f32x4*)(p + 4);
    bf16x8 r;
    r[0] = f2bf(x0[0]); r[1] = f2bf(x0[1]); r[2] = f2bf(x0[2]); r[3] = f2bf(x0[3]);
    r[4] = f2bf(x1[0]); r[5] = f2bf(x1[1]); r[6] = f2bf(x1[2]); r[7] = f2bf(x1[3]);
    return r;
}
__device__ inline bf16x8 loadAB(const short* p) {
    return *(const bf16x8*)p;
}

// C(M,N) = A(M,K) * B(N,K)^T, fp32 accum, bf16 MFMA.
// 64x64 tile per block, 4 waves (2x2), each wave 32x32 (2x2 fragments).
// OUT_BF16=false -> float32 output (d_out is float* per reference dtype).
template <typename TA, typename TB, bool OUT_BF16>
__global__ __launch_bounds__(256) void gemm_bt(const TA* __restrict__ A,
                                               const TB* __restrict__ Bm,
                                               void* __restrict__ Cv,
                                               int M, int N, int K) {
    int ntn = N >> 6;
    int m0 = (blockIdx.x / ntn) << 6;
    int n0 = (blockIdx.x % ntn) << 6;
    int wid = threadIdx.x >> 6, l = threadIdx.x & 63;
    int wr = wid >> 1, wc = wid & 1;
    int c = l & 15, g = l >> 4;

    f32x4 acc[2][2] = {};
    const TA* Ap0 = A + (size_t)(m0 + wr * 32 + c) * K + g * 8;
    const TA* Ap1 = Ap0 + (size_t)16 * K;
    const TB* Bp0 = Bm + (size_t)(n0 + wc * 32 + c) * K + g * 8;
    const TB* Bp1 = Bp0 + (size_t)16 * K;

    for (int k0 = 0; k0 < K; k0 += 32) {
        bf16x8 a0 = loadAB(Ap0 + k0);
        bf16x8 a1 = loadAB(Ap1 + k0);
        bf16x8 b0 = loadAB(Bp0 + k0);
        bf16x8 b1 = loadAB(Bp1 + k0);
        acc[0][0] = __builtin_amdgcn_mfma_f32_16x16x32_bf16(a0, b0, acc[0][0], 0, 0, 0);
        acc[0][1] = __builtin_amdgcn_mfma_f32_16x16x32_bf16(a0, b1, acc[0][1], 0, 0, 0);
        acc[1][0] = __builtin_amdgcn_mfma_f32_16x16x32_bf16(a1, b0, acc[1][0], 0, 0, 0);
        acc[1][1] = __builtin_amdgcn_mfma_f32_16x16x32_bf16(a1, b1, acc[1][1], 0, 0, 0);
    }

    for (int i = 0; i < 2; i++)
        for (int j = 0; j < 2; j++)
            for (int r = 0; r < 4; r++) {
                int rr = m0 + wr * 32 + i * 16 + g * 4 + r;   // C/D row = (l>>4)*4 + reg
                int cc = n0 + wc * 32 + j * 16 + c;           // C/D col = l&15
                if (OUT_BF16)
                    ((short*)Cv)[(size_t)rr * N + cc] = f2bf(acc[i][j][r]);
                else
                    ((float*)Cv)[(size_t)rr * N + cc] = acc[i][j][r];
            }
}

// Causal depthwise conv1d (K=3) + bias; splits qkv -> Q (B,H,T,64, scaled 1/8),
// K (B,T,64), V transposed (B,64,T). All bf16 out.
__global__ __launch_bounds__(256) void conv_split(const float* __restrict__ qkv,
        const float* __restrict__ qw, const float* __restrict__ qb,
        const float* __restrict__ kw, const float* __restrict__ kbias,
        const float* __restrict__ vw, const float* __restrict__ vbias,
        short* __restrict__ Qs, short* __restrict__ Kb, short* __restrict__ Vt) {
    int idx = blockIdx.x * 256 + threadIdx.x;
    int ch = idx % O_;
    int bt = idx / O_;
    int t = bt % T_;
    int b = bt / T_;
    const float* p = qkv + (size_t)bt * O_ + ch;
    float x2 = p[0];
    float x1 = (t >= 1) ? p[-O_] : 0.f;
    float x0 = (t >= 2) ? p[-2 * O_] : 0.f;
    float w0, w1, w2, bias;
    if (ch < C_)             { w0 = qw[ch*3]; w1 = qw[ch*3+1]; w2 = qw[ch*3+2]; bias = qb[ch]; }
    else if (ch < C_ + HD_)  { int cc = ch - C_;       w0 = kw[cc*3]; w1 = kw[cc*3+1]; w2 = kw[cc*3+2]; bias = kbias[cc]; }
    else                     { int cc = ch - C_ - HD_; w0 = vw[cc*3]; w1 = vw[cc*3+1]; w2 = vw[cc*3+2]; bias = vbias[cc]; }
    float y = fmaf(x0, w0, fmaf(x1, w1, fmaf(x2, w2, bias)));
    if (ch < C_) {
        int h = ch >> 6, d = ch & 63;
        Qs[(((size_t)b * H_ + h) * T_ + t) * HD_ + d] = f2bf(y * 0.125f);
    } else if (ch < C_ + HD_) {
        Kb[((size_t)b * T_ + t) * HD_ + (ch - C_)] = f2bf(y);
    } else {
        Vt[((size_t)b * HD_ + (ch - C_ - HD_)) * T_ + t] = f2bf(y);
    }
}

// Flash-style causal MQA. Block = 4 waves; wave w owns q-rows [qt0+16w, qt0+16w+16).
// KV tiles of 64. Scores: MFMA(Q-frag, K-frag). P relayout via per-wave LDS tile.
// PV: MFMA(P-frag, Vt-frag) with V pre-transposed (B,64,T).
__global__ __launch_bounds__(256) void attn_kernel(const short* __restrict__ Qs,
        const short* __restrict__ Kb, const short* __restrict__ Vt,
        short* __restrict__ Y) {
    __shared__ __align__(16) short P_lds[4][16][72];  // +8 pad: 16B-aligned rows, low conflicts
    int b = blockIdx.y >> 4;
    int h = blockIdx.y & 15;
    int wid = threadIdx.x >> 6, l = threadIdx.x & 63;
    int c = l & 15, g = l >> 4;
    int qbase = blockIdx.x * 64 + wid * 16;

    const short* Qp = Qs + ((size_t)blockIdx.y * T_ + qbase + c) * HD_;
    bf16x8 qa0 = *(const bf16x8*)(Qp + g * 8);
    bf16x8 qa1 = *(const bf16x8*)(Qp + 32 + g * 8);

    f32x4 Oa[4] = {};
    float m[4], lsum[4];
    for (int r = 0; r < 4; r++) { m[r] = -1e30f; lsum[r] = 0.f; }

    const short* Kbase = Kb + (size_t)b * T_ * HD_;
    const short* Vbase = Vt + (size_t)b * HD_ * T_;

    for (int kt0 = 0; kt0 < qbase + 16; kt0 += 64) {
        // ---- scores: 16 x 64 tile, 4 col-fragments ----
        f32x4 sc[4];
        for (int n = 0; n < 4; n++) {
            const short* Kp = Kbase + (size_t)(kt0 + n * 16 + c) * HD_ + g * 8;
            bf16x8 k0 = *(const bf16x8*)Kp;
            bf16x8 k1 = *(const bf16x8*)(Kp + 32);
            f32x4 z = {};
            z = __builtin_amdgcn_mfma_f32_16x16x32_bf16(qa0, k0, z, 0, 0, 0);
            z = __builtin_amdgcn_mfma_f32_16x16x32_bf16(qa1, k1, z, 0, 0, 0);
            sc[n] = z;
        }
        // ---- causal mask (scale already folded into Q) ----
        if (kt0 + 63 > qbase) {
            for (int n = 0; n < 4; n++) {
                int ki = kt0 + n * 16 + c;
                for (int r = 0; r < 4; r++) {
                    int qi = qbase + g * 4 + r;
                    if (ki > qi) sc[n][r] = -1e30f;
                }
            }
        }
        // ---- online softmax (rows live in 16-lane groups) ----
        for (int r = 0; r < 4; r++) {
            float mx = fmaxf(fmaxf(sc[0][r], sc[1][r]), fmaxf(sc[2][r], sc[3][r]));
            for (int off = 1; off < 16; off <<= 1) mx = fmaxf(mx, __shfl_xor(mx, off, 64));
            float nm = fmaxf(m[r], mx);
            float alpha = __expf(m[r] - nm);
            float s_ = 0.f;
            for (int n = 0; n < 4; n++) {
                float pv = __expf(sc[n][r] - nm);
                sc[n][r] = pv;
                s_ += pv;
            }
            for (int off = 1; off < 16; off <<= 1) s_ += __shfl_xor(s_, off, 64);
            lsum[r] = lsum[r] * alpha + s_;
            m[r] = nm;
            for (int j = 0; j < 4; j++) Oa[j][r] *= alpha;
        }
        // ---- P: C/D layout -> A-frag layout via per-wave LDS tile ----
        for (int n = 0; n < 4; n++)
            for (int r = 0; r < 4; r++)
                P_lds[wid][g * 4 + r][n * 16 + c] = f2bf(sc[n][r]);
        // Same-wave write->read: LDS ops are in-order per wave in HW, but pin
        // the compiler too (guide rule #18): drain lgkm + block reordering.
        asm volatile("s_waitcnt lgkmcnt(0)" ::: "memory");
        __builtin_amdgcn_sched_barrier(0);
        for (int ks = 0; ks < 2; ks++) {
            bf16x8 pa = *(const bf16x8*)&P_lds[wid][c][ks * 32 + g * 8];
            for (int j = 0; j < 4; j++) {
                const short* Vp = Vbase + (size_t)(j * 16 + c) * T_ + kt0 + ks * 32 + g * 8;
                bf16x8 vbf = *(const bf16x8*)Vp;
                Oa[j] = __builtin_amdgcn_mfma_f32_16x16x32_bf16(pa, vbf, Oa[j], 0, 0, 0);
            }
        }
    }
    // ---- epilogue: normalize, write y (B,T,C) bf16 ----
    for (int r = 0; r < 4; r++) {
        float inv = 1.f / lsum[r];
        int qi = qbase + g * 4 + r;
        size_t orow = ((size_t)b * T_ + qi) * C_ + h * HD_;
        for (int j = 0; j < 4; j++)
            Y[orow + j * 16 + c] = f2bf(Oa[j][r] * inv);
    }
}

extern "C" void kernel_launch(void* const* d_in, const int* in_sizes, int n_in,
                              void* d_out, int out_size, void* d_ws, size_t ws_size,
                              hipStream_t stream) {
    const float* x     = (const float*)d_in[0];
    const float* Wqkv  = (const float*)d_in[1];
    const float* qw    = (const float*)d_in[2];
    const float* qb    = (const float*)d_in[3];
    const float* kw    = (const float*)d_in[4];
    const float* kbias = (const float*)d_in[5];
    const float* vw    = (const float*)d_in[6];
    const float* vbias = (const float*)d_in[7];
    const float* Wproj = (const float*)d_in[8];

    char* ws = (char*)d_ws;
    float* qkv = (float*)ws;                                   // B*T*1152 f32  = 18874368 B
    short* Qsc = (short*)(ws + 18874368);                      // B*H*T*64 bf16 =  8388608 B
    short* Kbf = (short*)(ws + 18874368 + 8388608);            // B*T*64  bf16  =   524288 B
    short* Vtr = (short*)(ws + 18874368 + 8388608 + 524288);   // B*64*T  bf16  =   524288 B
    short* Ybf = (short*)(ws + 18874368 + 8388608 + 1048576);  // B*T*C   bf16  =  8388608 B

    const int M = B_ * T_;  // 4096

    // 1) qkv = x @ Wqkv^T
    gemm_bt<float, float, false><<<dim3((M / 64) * (O_ / 64)), 256, 0, stream>>>(
        x, Wqkv, qkv, M, O_, C_);

    // 2) causal dwconv + split + scale + V-transpose
    conv_split<<<dim3((B_ * T_ * O_) / 256), 256, 0, stream>>>(
        qkv, qw, qb, kw, kbias, vw, vbias, Qsc, Kbf, Vtr);

    // 3) causal MQA attention -> y (B,T,C) bf16
    attn_kernel<<<dim3(T_ / 64, B_ * H_), 256, 0, stream>>>(Qsc, Kbf, Vtr, Ybf);

    // 4) out = y @ Wproj^T -> FLOAT32 d_out (reference output dtype is f32)
    gemm_bt<short, float, false><<<dim3((M / 64) * (C_ / 64)), 256, 0, stream>>>(
        Ybf, Wproj, (float*)d_out, M, C_, C_);
}

// Round 5
// 341.422 us; speedup vs baseline: 1.3886x; 1.3886x over previous
//
#include <hip/hip_runtime.h>
#include <hip/hip_bf16.h>

#define B_ 2
#define T_ 2048
#define C_ 1024
#define H_ 16
#define HD_ 64
#define O_ 1152   // C + 2*HD
#define KVB 128   // attention K/V tile

#define NX  (B_ * T_ * C_)      // 4194304
#define NW1 (O_ * C_)           // 1179648
#define NW2 (C_ * C_)           // 1048576

typedef __attribute__((ext_vector_type(8))) short bf16x8;
typedef __attribute__((ext_vector_type(4))) float f32x4;

__device__ inline short f2bf(float f) {
    union { float f; unsigned u; } v; v.f = f;
    unsigned r = v.u + 0x7FFFu + ((v.u >> 16) & 1u);
    return (short)(r >> 16);
}
__device__ inline float bf2f(short s) {
    union { unsigned u; float f; } v; v.u = ((unsigned)(unsigned short)s) << 16;
    return v.f;
}

__device__ inline bf16x8 loadAB(const short* p) { return *(const bf16x8*)p; }

// -------- f32 -> bf16 pre-conversion of x, Wqkv, Wproj (one launch) --------
__global__ __launch_bounds__(256) void cvt_bf16(const float* __restrict__ x,
        const float* __restrict__ w1, const float* __restrict__ w2,
        short* __restrict__ xb, short* __restrict__ w1b, short* __restrict__ w2b) {
    size_t i = ((size_t)blockIdx.x * 256 + threadIdx.x) * 8;
    const float* src; short* dst; size_t off;
    if (i < (size_t)NX)              { src = x;  dst = xb;  off = i; }
    else if (i < (size_t)NX + NW1)   { src = w1; dst = w1b; off = i - NX; }
    else                             { src = w2; dst = w2b; off = i - NX - NW1; }
    f32x4 a = *(const f32x4*)(src + off);
    f32x4 b = *(const f32x4*)(src + off + 4);
    bf16x8 r;
    r[0] = f2bf(a[0]); r[1] = f2bf(a[1]); r[2] = f2bf(a[2]); r[3] = f2bf(a[3]);
    r[4] = f2bf(b[0]); r[5] = f2bf(b[1]); r[6] = f2bf(b[2]); r[7] = f2bf(b[3]);
    *(bf16x8*)(dst + off) = r;
}

// C(M,N) = A(M,K) * B(N,K)^T, bf16 inputs, fp32 accum.
// 64x64 tile per block, 4 waves (2x2), each wave 32x32 (2x2 fragments).
template <bool OUT_BF16>
__global__ __launch_bounds__(256) void gemm_bt(const short* __restrict__ A,
                                               const short* __restrict__ Bm,
                                               void* __restrict__ Cv,
                                               int M, int N, int K) {
    int ntn = N >> 6;
    int m0 = (blockIdx.x / ntn) << 6;
    int n0 = (blockIdx.x % ntn) << 6;
    int wid = threadIdx.x >> 6, l = threadIdx.x & 63;
    int wr = wid >> 1, wc = wid & 1;
    int c = l & 15, g = l >> 4;

    f32x4 acc[2][2] = {};
    const short* Ap0 = A + (size_t)(m0 + wr * 32 + c) * K + g * 8;
    const short* Ap1 = Ap0 + (size_t)16 * K;
    const short* Bp0 = Bm + (size_t)(n0 + wc * 32 + c) * K + g * 8;
    const short* Bp1 = Bp0 + (size_t)16 * K;

    for (int k0 = 0; k0 < K; k0 += 32) {
        bf16x8 a0 = loadAB(Ap0 + k0);
        bf16x8 a1 = loadAB(Ap1 + k0);
        bf16x8 b0 = loadAB(Bp0 + k0);
        bf16x8 b1 = loadAB(Bp1 + k0);
        acc[0][0] = __builtin_amdgcn_mfma_f32_16x16x32_bf16(a0, b0, acc[0][0], 0, 0, 0);
        acc[0][1] = __builtin_amdgcn_mfma_f32_16x16x32_bf16(a0, b1, acc[0][1], 0, 0, 0);
        acc[1][0] = __builtin_amdgcn_mfma_f32_16x16x32_bf16(a1, b0, acc[1][0], 0, 0, 0);
        acc[1][1] = __builtin_amdgcn_mfma_f32_16x16x32_bf16(a1, b1, acc[1][1], 0, 0, 0);
    }

    for (int i = 0; i < 2; i++)
        for (int j = 0; j < 2; j++)
            for (int r = 0; r < 4; r++) {
                int rr = m0 + wr * 32 + i * 16 + g * 4 + r;   // C/D row = (l>>4)*4 + reg
                int cc = n0 + wc * 32 + j * 16 + c;           // C/D col = l&15
                if (OUT_BF16)
                    ((short*)Cv)[(size_t)rr * N + cc] = f2bf(acc[i][j][r]);
                else
                    ((float*)Cv)[(size_t)rr * N + cc] = acc[i][j][r];
            }
}

// Causal depthwise conv1d (K=3) + bias on bf16 qkv; splits -> Q (B,H,T,64,
// scaled 1/8), K (B,T,64), V transposed (B,64,T). All bf16.
__global__ __launch_bounds__(256) void conv_split(const short* __restrict__ qkv,
        const float* __restrict__ qw, const float* __restrict__ qb,
        const float* __restrict__ kw, const float* __restrict__ kbias,
        const float* __restrict__ vw, const float* __restrict__ vbias,
        short* __restrict__ Qs, short* __restrict__ Kb, short* __restrict__ Vt) {
    int idx = blockIdx.x * 256 + threadIdx.x;
    int ch = idx % O_;
    int bt = idx / O_;
    int t = bt % T_;
    int b = bt / T_;
    const short* p = qkv + (size_t)bt * O_ + ch;
    float x2 = bf2f(p[0]);
    float x1 = (t >= 1) ? bf2f(p[-O_]) : 0.f;
    float x0 = (t >= 2) ? bf2f(p[-2 * O_]) : 0.f;
    float w0, w1, w2, bias;
    if (ch < C_)             { w0 = qw[ch*3]; w1 = qw[ch*3+1]; w2 = qw[ch*3+2]; bias = qb[ch]; }
    else if (ch < C_ + HD_)  { int cc = ch - C_;       w0 = kw[cc*3]; w1 = kw[cc*3+1]; w2 = kw[cc*3+2]; bias = kbias[cc]; }
    else                     { int cc = ch - C_ - HD_; w0 = vw[cc*3]; w1 = vw[cc*3+1]; w2 = vw[cc*3+2]; bias = vbias[cc]; }
    float y = fmaf(x0, w0, fmaf(x1, w1, fmaf(x2, w2, bias)));
    if (ch < C_) {
        int h = ch >> 6, d = ch & 63;
        Qs[(((size_t)b * H_ + h) * T_ + t) * HD_ + d] = f2bf(y * 0.125f);
    } else if (ch < C_ + HD_) {
        Kb[((size_t)b * T_ + t) * HD_ + (ch - C_)] = f2bf(y);
    } else {
        Vt[((size_t)b * HD_ + (ch - C_ - HD_)) * T_ + t] = f2bf(y);
    }
}

// Flash-style causal MQA, v2: 1 wave per block (fine-grain balance), 16 q-rows
// per wave, KV tiles of 128 (fewer serial softmax chains per unit work),
// heavy tiles dispatched first (reversed blockIdx.x). No explicit LDS fence:
// same-wave ds_write->ds_read ordering is compiler-tracked, letting next-tile
// K/V loads overlap softmax.
__global__ __launch_bounds__(64) void attn_kernel(const short* __restrict__ Qs,
        const short* __restrict__ Kb, const short* __restrict__ Vt,
        short* __restrict__ Y) {
    __shared__ __align__(16) short P_lds[16][KVB + 8];  // +16B pad per row
    int qt = gridDim.x - 1 - blockIdx.x;   // heavy (large qbase) first
    int b = blockIdx.y >> 4;
    int h = blockIdx.y & 15;
    int l = threadIdx.x;          // 0..63, one wave
    int c = l & 15, g = l >> 4;
    int qbase = qt * 16;

    const short* Qp = Qs + ((size_t)blockIdx.y * T_ + qbase + c) * HD_;
    bf16x8 qa0 = *(const bf16x8*)(Qp + g * 8);
    bf16x8 qa1 = *(const bf16x8*)(Qp + 32 + g * 8);

    f32x4 Oa[4] = {};
    float m[4], lsum[4];
    for (int r = 0; r < 4; r++) { m[r] = -1e30f; lsum[r] = 0.f; }

    const short* Kbase = Kb + (size_t)b * T_ * HD_;
    const short* Vbase = Vt + (size_t)b * HD_ * T_;

    for (int kt0 = 0; kt0 < qbase + 16; kt0 += KVB) {
        // ---- scores: 16 x 128 tile, 8 col-fragments ----
        f32x4 sc[8];
        for (int n = 0; n < 8; n++) {
            const short* Kp = Kbase + (size_t)(kt0 + n * 16 + c) * HD_ + g * 8;
            bf16x8 k0 = *(const bf16x8*)Kp;
            bf16x8 k1 = *(const bf16x8*)(Kp + 32);
            f32x4 z = {};
            z = __builtin_amdgcn_mfma_f32_16x16x32_bf16(qa0, k0, z, 0, 0, 0);
            z = __builtin_amdgcn_mfma_f32_16x16x32_bf16(qa1, k1, z, 0, 0, 0);
            sc[n] = z;
        }
        // ---- causal mask (scale folded into Q) ----
        if (kt0 + KVB - 1 > qbase) {
            for (int n = 0; n < 8; n++) {
                int ki = kt0 + n * 16 + c;
                for (int r = 0; r < 4; r++) {
                    int qi = qbase + g * 4 + r;
                    if (ki > qi) sc[n][r] = -1e30f;
                }
            }
        }
        // ---- online softmax (row q=g*4+r lives in the 16 lanes of group g) ----
        for (int r = 0; r < 4; r++) {
            float mx = fmaxf(fmaxf(fmaxf(sc[0][r], sc[1][r]), fmaxf(sc[2][r], sc[3][r])),
                             fmaxf(fmaxf(sc[4][r], sc[5][r]), fmaxf(sc[6][r], sc[7][r])));
            for (int off = 1; off < 16; off <<= 1) mx = fmaxf(mx, __shfl_xor(mx, off, 64));
            float nm = fmaxf(m[r], mx);
            float alpha = __expf(m[r] - nm);
            float s_ = 0.f;
            for (int n = 0; n < 8; n++) {
                float pv = __expf(sc[n][r] - nm);
                sc[n][r] = pv;
                s_ += pv;
            }
            for (int off = 1; off < 16; off <<= 1) s_ += __shfl_xor(s_, off, 64);
            lsum[r] = lsum[r] * alpha + s_;
            m[r] = nm;
            for (int j = 0; j < 4; j++) Oa[j][r] *= alpha;
        }
        // ---- P: C/D layout -> A-frag layout via LDS (same-wave, no barrier) ----
        for (int n = 0; n < 8; n++)
            for (int r = 0; r < 4; r++)
                P_lds[g * 4 + r][n * 16 + c] = f2bf(sc[n][r]);
        for (int ks = 0; ks < 4; ks++) {
            bf16x8 pa = *(const bf16x8*)&P_lds[c][ks * 32 + g * 8];
            for (int j = 0; j < 4; j++) {
                const short* Vp = Vbase + (size_t)(j * 16 + c) * T_ + kt0 + ks * 32 + g * 8;
                bf16x8 vbf = *(const bf16x8*)Vp;
                Oa[j] = __builtin_amdgcn_mfma_f32_16x16x32_bf16(pa, vbf, Oa[j], 0, 0, 0);
            }
        }
    }
    // ---- epilogue: normalize, write y (B,T,C) bf16 ----
    for (int r = 0; r < 4; r++) {
        float inv = 1.f / lsum[r];
        int qi = qbase + g * 4 + r;
        size_t orow = ((size_t)b * T_ + qi) * C_ + h * HD_;
        for (int j = 0; j < 4; j++)
            Y[orow + j * 16 + c] = f2bf(Oa[j][r] * inv);
    }
}

extern "C" void kernel_launch(void* const* d_in, const int* in_sizes, int n_in,
                              void* d_out, int out_size, void* d_ws, size_t ws_size,
                              hipStream_t stream) {
    const float* x     = (const float*)d_in[0];
    const float* Wqkv  = (const float*)d_in[1];
    const float* qw    = (const float*)d_in[2];
    const float* qb    = (const float*)d_in[3];
    const float* kw    = (const float*)d_in[4];
    const float* kbias = (const float*)d_in[5];
    const float* vw    = (const float*)d_in[6];
    const float* vbias = (const float*)d_in[7];
    const float* Wproj = (const float*)d_in[8];

    char* ws = (char*)d_ws;
    short* xb     = (short*)ws;                    //  8388608 B (reused as Ybf later)
    short* Wqkvb  = (short*)(ws + 8388608);        //  2359296 B
    short* Wprojb = (short*)(ws + 10747904);       //  2097152 B
    short* qkvb   = (short*)(ws + 12845056);       //  9437184 B
    short* Qsc    = (short*)(ws + 22282240);       //  8388608 B
    short* Kbf    = (short*)(ws + 30670848);       //   524288 B
    short* Vtr    = (short*)(ws + 31195136);       //   524288 B  (total 31.7 MB)
    short* Ybf    = xb;                            // x dead after gemm1

    const int M = B_ * T_;  // 4096

    // 0) f32 -> bf16: x, Wqkv, Wproj   (6422528 elems / 8 per thread / 256)
    cvt_bf16<<<dim3(3136), 256, 0, stream>>>(x, Wqkv, Wproj, xb, Wqkvb, Wprojb);

    // 1) qkv = x @ Wqkv^T  (bf16 out)
    gemm_bt<true><<<dim3((M / 64) * (O_ / 64)), 256, 0, stream>>>(
        xb, Wqkvb, qkvb, M, O_, C_);

    // 2) causal dwconv + split + scale + V-transpose
    conv_split<<<dim3((B_ * T_ * O_) / 256), 256, 0, stream>>>(
        qkvb, qw, qb, kw, kbias, vw, vbias, Qsc, Kbf, Vtr);

    // 3) causal MQA attention -> y (B,T,C) bf16
    attn_kernel<<<dim3(T_ / 16, B_ * H_), 64, 0, stream>>>(Qsc, Kbf, Vtr, Ybf);

    // 4) out = y @ Wproj^T -> f32 d_out
    gemm_bt<false><<<dim3((M / 64) * (C_ / 64)), 256, 0, stream>>>(
        Ybf, Wprojb, (float*)d_out, M, C_, C_);
}

// Round 6
// 227.888 us; speedup vs baseline: 2.0804x; 1.4982x over previous
//
#include <hip/hip_runtime.h>
#include <hip/hip_bf16.h>

#define B_ 2
#define T_ 2048
#define C_ 1024
#define H_ 16
#define HD_ 64
#define O_ 1152   // C + 2*HD

#define NX  (B_ * T_ * C_)      // 4194304
#define NW1 (O_ * C_)           // 1179648
#define NW2 (C_ * C_)           // 1048576

typedef __attribute__((ext_vector_type(8))) short bf16x8;
typedef __attribute__((ext_vector_type(4))) float f32x4;
typedef __attribute__((ext_vector_type(16))) float f32x16;
typedef __attribute__((ext_vector_type(4))) unsigned u32x4;

__device__ inline short f2bf(float f) {
    union { float f; unsigned u; } v; v.f = f;
    unsigned r = v.u + 0x7FFFu + ((v.u >> 16) & 1u);
    return (short)(r >> 16);
}
__device__ inline float bf2f(short s) {
    union { unsigned u; float f; } v; v.u = ((unsigned)(unsigned short)s) << 16;
    return v.f;
}
// packed bf16(lo) | bf16(hi)<<16, RNE
__device__ inline unsigned cvtpk(float lo, float hi) {
    unsigned r;
    asm("v_cvt_pk_bf16_f32 %0, %1, %2" : "=v"(r) : "v"(lo), "v"(hi));
    return r;
}

__device__ inline bf16x8 loadAB(const short* p) { return *(const bf16x8*)p; }

// -------- f32 -> bf16 pre-conversion of x, Wqkv, Wproj (one launch) --------
__global__ __launch_bounds__(256) void cvt_bf16(const float* __restrict__ x,
        const float* __restrict__ w1, const float* __restrict__ w2,
        short* __restrict__ xb, short* __restrict__ w1b, short* __restrict__ w2b) {
    size_t i = ((size_t)blockIdx.x * 256 + threadIdx.x) * 8;
    const float* src; short* dst; size_t off;
    if (i < (size_t)NX)              { src = x;  dst = xb;  off = i; }
    else if (i < (size_t)NX + NW1)   { src = w1; dst = w1b; off = i - NX; }
    else                             { src = w2; dst = w2b; off = i - NX - NW1; }
    f32x4 a = *(const f32x4*)(src + off);
    f32x4 b = *(const f32x4*)(src + off + 4);
    bf16x8 r;
    r[0] = f2bf(a[0]); r[1] = f2bf(a[1]); r[2] = f2bf(a[2]); r[3] = f2bf(a[3]);
    r[4] = f2bf(b[0]); r[5] = f2bf(b[1]); r[6] = f2bf(b[2]); r[7] = f2bf(b[3]);
    *(bf16x8*)(dst + off) = r;
}

// C(M,N) = A(M,K) * B(N,K)^T, bf16 inputs, fp32 accum.
// 64x64 tile per block, 4 waves (2x2), each wave 32x32 (2x2 fragments).
template <bool OUT_BF16>
__global__ __launch_bounds__(256) void gemm_bt(const short* __restrict__ A,
                                               const short* __restrict__ Bm,
                                               void* __restrict__ Cv,
                                               int M, int N, int K) {
    int ntn = N >> 6;
    int m0 = (blockIdx.x / ntn) << 6;
    int n0 = (blockIdx.x % ntn) << 6;
    int wid = threadIdx.x >> 6, l = threadIdx.x & 63;
    int wr = wid >> 1, wc = wid & 1;
    int c = l & 15, g = l >> 4;

    f32x4 acc[2][2] = {};
    const short* Ap0 = A + (size_t)(m0 + wr * 32 + c) * K + g * 8;
    const short* Ap1 = Ap0 + (size_t)16 * K;
    const short* Bp0 = Bm + (size_t)(n0 + wc * 32 + c) * K + g * 8;
    const short* Bp1 = Bp0 + (size_t)16 * K;

    for (int k0 = 0; k0 < K; k0 += 32) {
        bf16x8 a0 = loadAB(Ap0 + k0);
        bf16x8 a1 = loadAB(Ap1 + k0);
        bf16x8 b0 = loadAB(Bp0 + k0);
        bf16x8 b1 = loadAB(Bp1 + k0);
        acc[0][0] = __builtin_amdgcn_mfma_f32_16x16x32_bf16(a0, b0, acc[0][0], 0, 0, 0);
        acc[0][1] = __builtin_amdgcn_mfma_f32_16x16x32_bf16(a0, b1, acc[0][1], 0, 0, 0);
        acc[1][0] = __builtin_amdgcn_mfma_f32_16x16x32_bf16(a1, b0, acc[1][0], 0, 0, 0);
        acc[1][1] = __builtin_amdgcn_mfma_f32_16x16x32_bf16(a1, b1, acc[1][1], 0, 0, 0);
    }

    for (int i = 0; i < 2; i++)
        for (int j = 0; j < 2; j++)
            for (int r = 0; r < 4; r++) {
                int rr = m0 + wr * 32 + i * 16 + g * 4 + r;   // C/D row = (l>>4)*4 + reg
                int cc = n0 + wc * 32 + j * 16 + c;           // C/D col = l&15
                if (OUT_BF16)
                    ((short*)Cv)[(size_t)rr * N + cc] = f2bf(acc[i][j][r]);
                else
                    ((float*)Cv)[(size_t)rr * N + cc] = acc[i][j][r];
            }
}

// Causal depthwise conv1d (K=3) + bias on bf16 qkv; splits -> Q (B,H,T,64,
// scaled 1/8), K (B,T,64), V transposed (B,64,T). All bf16.
__global__ __launch_bounds__(256) void conv_split(const short* __restrict__ qkv,
        const float* __restrict__ qw, const float* __restrict__ qb,
        const float* __restrict__ kw, const float* __restrict__ kbias,
        const float* __restrict__ vw, const float* __restrict__ vbias,
        short* __restrict__ Qs, short* __restrict__ Kb, short* __restrict__ Vt) {
    int idx = blockIdx.x * 256 + threadIdx.x;
    int ch = idx % O_;
    int bt = idx / O_;
    int t = bt % T_;
    int b = bt / T_;
    const short* p = qkv + (size_t)bt * O_ + ch;
    float x2 = bf2f(p[0]);
    float x1 = (t >= 1) ? bf2f(p[-O_]) : 0.f;
    float x0 = (t >= 2) ? bf2f(p[-2 * O_]) : 0.f;
    float w0, w1, w2, bias;
    if (ch < C_)             { w0 = qw[ch*3]; w1 = qw[ch*3+1]; w2 = qw[ch*3+2]; bias = qb[ch]; }
    else if (ch < C_ + HD_)  { int cc = ch - C_;       w0 = kw[cc*3]; w1 = kw[cc*3+1]; w2 = kw[cc*3+2]; bias = kbias[cc]; }
    else                     { int cc = ch - C_ - HD_; w0 = vw[cc*3]; w1 = vw[cc*3+1]; w2 = vw[cc*3+2]; bias = vbias[cc]; }
    float y = fmaf(x0, w0, fmaf(x1, w1, fmaf(x2, w2, bias)));
    if (ch < C_) {
        int h = ch >> 6, d = ch & 63;
        Qs[(((size_t)b * H_ + h) * T_ + t) * HD_ + d] = f2bf(y * 0.125f);
    } else if (ch < C_ + HD_) {
        Kb[((size_t)b * T_ + t) * HD_ + (ch - C_)] = f2bf(y);
    } else {
        Vt[((size_t)b * HD_ + (ch - C_ - HD_)) * T_ + t] = f2bf(y);
    }
}

// Flash-style causal MQA, v3 (m214-style swapped QK^T, 32x32x16 MFMA).
// 4 independent waves/block, each owns 32 q-rows (qt balanced-paired so every
// block has equal triangular work). Per KV-64 tile:
//   S^T = mfma(K_tile, Q)  -> lane holds one q-row's scores in-lane
//   softmax: 31 in-lane ops + ONE shfl_xor(32); no 16-lane trees, no LDS
//   P -> bf16 B-frags via v_cvt_pk + lane^32 exchange (T12 recipe)
//   O^T += mfma(Vt_frag, P_frag); V pre-transposed (B,64,T)
// C/D layout (m74-verified): col=lane&31, row=(reg&3)+8*(reg>>2)+4*(lane>>5).
__global__ __launch_bounds__(256) void attn_kernel(const short* __restrict__ Qs,
        const short* __restrict__ Kb, const short* __restrict__ Vt,
        short* __restrict__ Y) {
    int bh = blockIdx.y;
    int b = bh >> 4;
    int h = bh & 15;
    int wid = threadIdx.x >> 6, l = threadIdx.x & 63;
    int ql = l & 31, hi = l >> 5;
    int k2 = blockIdx.x;                       // 0..15
    int qt = (wid < 2) ? (2 * k2 + wid) : (63 - 2 * k2 - (wid & 1));
    int qbase = qt * 32;
    int qi = qbase + ql;

    // Q B-fragments, 4 contraction steps of 16 over HD=64 (col=q=ql, d=hi*8+j)
    const short* Qp = Qs + ((size_t)bh * T_ + qi) * HD_ + hi * 8;
    bf16x8 qf[4];
    #pragma unroll
    for (int s = 0; s < 4; s++) qf[s] = *(const bf16x8*)(Qp + s * 16);

    f32x16 Oa0 = {}, Oa1 = {};                 // O^T, d-blocks [0,32) and [32,64)
    float mrow = -1e30f, lsum = 0.f;

    const short* Kbase = Kb + (size_t)b * T_ * HD_;
    const short* Vbase = Vt + (size_t)b * HD_ * T_;

    int nt = (qt >> 1) + 1;
    for (int it = 0; it < nt; it++) {
        int kt0 = it * 64;
        // ---- S^T: two 32-row k-subtiles, contraction over d ----
        f32x16 sv0 = {}, sv1 = {};
        #pragma unroll
        for (int s = 0; s < 4; s++) {
            bf16x8 ka = *(const bf16x8*)(Kbase + (size_t)(kt0 + ql) * HD_ + s * 16 + hi * 8);
            sv0 = __builtin_amdgcn_mfma_f32_32x32x16_bf16(ka, qf[s], sv0, 0, 0, 0);
        }
        #pragma unroll
        for (int s = 0; s < 4; s++) {
            bf16x8 ka = *(const bf16x8*)(Kbase + (size_t)(kt0 + 32 + ql) * HD_ + s * 16 + hi * 8);
            sv1 = __builtin_amdgcn_mfma_f32_32x32x16_bf16(ka, qf[s], sv1, 0, 0, 0);
        }
        // ---- causal mask (last tile only; scale folded into Q) ----
        if (kt0 + 64 > qbase) {
            #pragma unroll
            for (int r = 0; r < 16; r++) {
                int kl = (r & 3) + 8 * (r >> 2) + 4 * hi;
                if (kt0 + kl > qi)      sv0[r] = -1e30f;
                if (kt0 + 32 + kl > qi) sv1[r] = -1e30f;
            }
        }
        // ---- online softmax: in-lane + one lane^32 exchange ----
        float pmax = sv0[0];
        #pragma unroll
        for (int r = 1; r < 16; r++) pmax = fmaxf(pmax, sv0[r]);
        #pragma unroll
        for (int r = 0; r < 16; r++) pmax = fmaxf(pmax, sv1[r]);
        pmax = fmaxf(pmax, __shfl_xor(pmax, 32, 64));
        float nm = fmaxf(mrow, pmax);
        float alpha = __expf(mrow - nm);
        mrow = nm;
        float psum = 0.f;
        #pragma unroll
        for (int r = 0; r < 16; r++) { sv0[r] = __expf(sv0[r] - nm); psum += sv0[r]; }
        #pragma unroll
        for (int r = 0; r < 16; r++) { sv1[r] = __expf(sv1[r] - nm); psum += sv1[r]; }
        psum += __shfl_xor(psum, 32, 64);
        lsum = lsum * alpha + psum;
        #pragma unroll
        for (int r = 0; r < 16; r++) { Oa0[r] *= alpha; Oa1[r] *= alpha; }
        // ---- P redistribution (cvt_pk + lane^32) + PV ----
        #pragma unroll
        for (int sub = 0; sub < 2; sub++) {
            #pragma unroll
            for (int hh = 0; hh < 2; hh++) {
                // X0..X3 pack this lane's 8 k-values (regs hh*8..hh*8+7)
                unsigned X0, X1, X2, X3;
                if (sub == 0) {
                    X0 = cvtpk(sv0[hh * 8 + 0], sv0[hh * 8 + 1]);
                    X1 = cvtpk(sv0[hh * 8 + 2], sv0[hh * 8 + 3]);
                    X2 = cvtpk(sv0[hh * 8 + 4], sv0[hh * 8 + 5]);
                    X3 = cvtpk(sv0[hh * 8 + 6], sv0[hh * 8 + 7]);
                } else {
                    X0 = cvtpk(sv1[hh * 8 + 0], sv1[hh * 8 + 1]);
                    X1 = cvtpk(sv1[hh * 8 + 2], sv1[hh * 8 + 3]);
                    X2 = cvtpk(sv1[hh * 8 + 4], sv1[hh * 8 + 5]);
                    X3 = cvtpk(sv1[hh * 8 + 6], sv1[hh * 8 + 7]);
                }
                unsigned sX0 = __shfl_xor(X0, 32, 64);
                unsigned sX1 = __shfl_xor(X1, 32, 64);
                unsigned sX2 = __shfl_xor(X2, 32, 64);
                unsigned sX3 = __shfl_xor(X3, 32, 64);
                union { u32x4 u; bf16x8 v; } pw;
                pw.u[0] = hi ? sX2 : X0;   // k elems (hi*8 + 0,1)
                pw.u[1] = hi ? sX3 : X1;   // k elems (hi*8 + 2,3)
                pw.u[2] = hi ? X2 : sX0;   // k elems (hi*8 + 4,5)
                pw.u[3] = hi ? X3 : sX1;   // k elems (hi*8 + 6,7)
                int koff = kt0 + sub * 32 + hh * 16 + hi * 8;
                bf16x8 va0 = *(const bf16x8*)(Vbase + (size_t)ql * T_ + koff);
                bf16x8 va1 = *(const bf16x8*)(Vbase + (size_t)(32 + ql) * T_ + koff);
                Oa0 = __builtin_amdgcn_mfma_f32_32x32x16_bf16(va0, pw.v, Oa0, 0, 0, 0);
                Oa1 = __builtin_amdgcn_mfma_f32_32x32x16_bf16(va1, pw.v, Oa1, 0, 0, 0);
            }
        }
    }
    // ---- epilogue: normalize, write one Y-row segment per lane ----
    float inv = 1.f / lsum;
    size_t orow = ((size_t)b * T_ + qi) * C_ + h * HD_;
    #pragma unroll
    for (int r = 0; r < 16; r += 2) {
        int d = (r & 3) + 8 * (r >> 2) + 4 * hi;       // r even -> d even; (r,r+1)->(d,d+1)
        *(unsigned*)(Y + orow + d)      = cvtpk(Oa0[r] * inv, Oa0[r + 1] * inv);
        *(unsigned*)(Y + orow + 32 + d) = cvtpk(Oa1[r] * inv, Oa1[r + 1] * inv);
    }
}

extern "C" void kernel_launch(void* const* d_in, const int* in_sizes, int n_in,
                              void* d_out, int out_size, void* d_ws, size_t ws_size,
                              hipStream_t stream) {
    const float* x     = (const float*)d_in[0];
    const float* Wqkv  = (const float*)d_in[1];
    const float* qw    = (const float*)d_in[2];
    const float* qb    = (const float*)d_in[3];
    const float* kw    = (const float*)d_in[4];
    const float* kbias = (const float*)d_in[5];
    const float* vw    = (const float*)d_in[6];
    const float* vbias = (const float*)d_in[7];
    const float* Wproj = (const float*)d_in[8];

    char* ws = (char*)d_ws;
    short* xb     = (short*)ws;                    //  8388608 B (reused as Ybf later)
    short* Wqkvb  = (short*)(ws + 8388608);        //  2359296 B
    short* Wprojb = (short*)(ws + 10747904);       //  2097152 B
    short* qkvb   = (short*)(ws + 12845056);       //  9437184 B
    short* Qsc    = (short*)(ws + 22282240);       //  8388608 B
    short* Kbf    = (short*)(ws + 30670848);       //   524288 B
    short* Vtr    = (short*)(ws + 31195136);       //   524288 B  (total 31.7 MB)
    short* Ybf    = xb;                            // x dead after gemm1

    const int M = B_ * T_;  // 4096

    // 0) f32 -> bf16: x, Wqkv, Wproj
    cvt_bf16<<<dim3(3136), 256, 0, stream>>>(x, Wqkv, Wproj, xb, Wqkvb, Wprojb);

    // 1) qkv = x @ Wqkv^T  (bf16 out)
    gemm_bt<true><<<dim3((M / 64) * (O_ / 64)), 256, 0, stream>>>(
        xb, Wqkvb, qkvb, M, O_, C_);

    // 2) causal dwconv + split + scale + V-transpose
    conv_split<<<dim3((B_ * T_ * O_) / 256), 256, 0, stream>>>(
        qkvb, qw, qb, kw, kbias, vw, vbias, Qsc, Kbf, Vtr);

    // 3) causal MQA attention -> y (B,T,C) bf16
    attn_kernel<<<dim3(16, B_ * H_), 256, 0, stream>>>(Qsc, Kbf, Vtr, Ybf);

    // 4) out = y @ Wproj^T -> f32 d_out
    gemm_bt<false><<<dim3((M / 64) * (C_ / 64)), 256, 0, stream>>>(
        Ybf, Wprojb, (float*)d_out, M, C_, C_);
}

// Round 7
// 189.505 us; speedup vs baseline: 2.5017x; 1.2025x over previous
//
#include <hip/hip_runtime.h>
#include <hip/hip_bf16.h>

#define B_ 2
#define T_ 2048
#define C_ 1024
#define H_ 16
#define HD_ 64
#define O_ 1152   // C + 2*HD

#define NX  (B_ * T_ * C_)      // 4194304
#define NW1 (O_ * C_)           // 1179648
#define NW2 (C_ * C_)           // 1048576

typedef __attribute__((ext_vector_type(8))) short bf16x8;
typedef __attribute__((ext_vector_type(4))) float f32x4;
typedef __attribute__((ext_vector_type(16))) float f32x16;
typedef __attribute__((ext_vector_type(4))) unsigned u32x4;

__device__ inline short f2bf(float f) {
    union { float f; unsigned u; } v; v.f = f;
    unsigned r = v.u + 0x7FFFu + ((v.u >> 16) & 1u);
    return (short)(r >> 16);
}
__device__ inline float bf2f(short s) {
    union { unsigned u; float f; } v; v.u = ((unsigned)(unsigned short)s) << 16;
    return v.f;
}
// packed bf16(lo) | bf16(hi)<<16, RNE
__device__ inline unsigned cvtpk(float lo, float hi) {
    unsigned r;
    asm("v_cvt_pk_bf16_f32 %0, %1, %2" : "=v"(r) : "v"(lo), "v"(hi));
    return r;
}

// -------- f32 -> bf16 pre-conversion of x, Wqkv, Wproj (one launch) --------
__global__ __launch_bounds__(256) void cvt_bf16(const float* __restrict__ x,
        const float* __restrict__ w1, const float* __restrict__ w2,
        short* __restrict__ xb, short* __restrict__ w1b, short* __restrict__ w2b) {
    size_t i = ((size_t)blockIdx.x * 256 + threadIdx.x) * 8;
    const float* src; short* dst; size_t off;
    if (i < (size_t)NX)              { src = x;  dst = xb;  off = i; }
    else if (i < (size_t)NX + NW1)   { src = w1; dst = w1b; off = i - NX; }
    else                             { src = w2; dst = w2b; off = i - NX - NW1; }
    f32x4 a = *(const f32x4*)(src + off);
    f32x4 b = *(const f32x4*)(src + off + 4);
    bf16x8 r;
    r[0] = f2bf(a[0]); r[1] = f2bf(a[1]); r[2] = f2bf(a[2]); r[3] = f2bf(a[3]);
    r[4] = f2bf(b[0]); r[5] = f2bf(b[1]); r[6] = f2bf(b[2]); r[7] = f2bf(b[3]);
    *(bf16x8*)(dst + off) = r;
}

// C(M,N) = A(M,K) * B(N,K)^T, bf16 inputs, fp32 accum.
// v2: 128x128 block tile, 4 waves (2x2), each wave 64x64 = 4x4 fragments of
// 16x16x32 -> 16 independent MFMAs per 8 loads per k-step (ILP >> v1's 4:4).
// XCD-aware block swizzle: n-consecutive blocks (sharing the A-panel) land on
// the same XCD's L2.
template <bool OUT_BF16>
__global__ __launch_bounds__(256) void gemm_bt(const short* __restrict__ A,
                                               const short* __restrict__ Bm,
                                               void* __restrict__ Cv,
                                               int M, int N, int K) {
    int ntn = N >> 7;
    int nwg = (M >> 7) * ntn;
    int cpx = nwg >> 3;                         // grids are %8 == 0
    int bid = (int)blockIdx.x;
    int swz = (bid % 8) * cpx + bid / 8;        // bijective XCD swizzle
    int m0 = (swz / ntn) << 7;
    int n0 = (swz % ntn) << 7;
    int wid = threadIdx.x >> 6, l = threadIdx.x & 63;
    int wr = wid >> 1, wc = wid & 1;
    int c = l & 15, g = l >> 4;

    f32x4 acc[4][4] = {};
    const short* Ap[4];
    const short* Bp[4];
    #pragma unroll
    for (int i = 0; i < 4; i++)
        Ap[i] = A + (size_t)(m0 + wr * 64 + i * 16 + c) * K + g * 8;
    #pragma unroll
    for (int j = 0; j < 4; j++)
        Bp[j] = Bm + (size_t)(n0 + wc * 64 + j * 16 + c) * K + g * 8;

    #pragma unroll 2
    for (int k0 = 0; k0 < K; k0 += 32) {
        bf16x8 a[4], b[4];
        #pragma unroll
        for (int i = 0; i < 4; i++) a[i] = *(const bf16x8*)(Ap[i] + k0);
        #pragma unroll
        for (int j = 0; j < 4; j++) b[j] = *(const bf16x8*)(Bp[j] + k0);
        #pragma unroll
        for (int i = 0; i < 4; i++)
            #pragma unroll
            for (int j = 0; j < 4; j++)
                acc[i][j] = __builtin_amdgcn_mfma_f32_16x16x32_bf16(a[i], b[j], acc[i][j], 0, 0, 0);
    }

    #pragma unroll
    for (int i = 0; i < 4; i++)
        #pragma unroll
        for (int j = 0; j < 4; j++)
            #pragma unroll
            for (int r = 0; r < 4; r++) {
                int rr = m0 + wr * 64 + i * 16 + g * 4 + r;   // C/D row = (l>>4)*4 + reg
                int cc = n0 + wc * 64 + j * 16 + c;           // C/D col = l&15
                if (OUT_BF16)
                    ((short*)Cv)[(size_t)rr * N + cc] = f2bf(acc[i][j][r]);
                else
                    ((float*)Cv)[(size_t)rr * N + cc] = acc[i][j][r];
            }
}

// Causal depthwise conv1d (K=3) + bias on bf16 qkv; splits -> Q (B,H,T,64,
// scaled 1/8), K (B,T,64), V transposed (B,64,T). All bf16.
__global__ __launch_bounds__(256) void conv_split(const short* __restrict__ qkv,
        const float* __restrict__ qw, const float* __restrict__ qb,
        const float* __restrict__ kw, const float* __restrict__ kbias,
        const float* __restrict__ vw, const float* __restrict__ vbias,
        short* __restrict__ Qs, short* __restrict__ Kb, short* __restrict__ Vt) {
    int idx = blockIdx.x * 256 + threadIdx.x;
    int ch = idx % O_;
    int bt = idx / O_;
    int t = bt % T_;
    int b = bt / T_;
    const short* p = qkv + (size_t)bt * O_ + ch;
    float x2 = bf2f(p[0]);
    float x1 = (t >= 1) ? bf2f(p[-O_]) : 0.f;
    float x0 = (t >= 2) ? bf2f(p[-2 * O_]) : 0.f;
    float w0, w1, w2, bias;
    if (ch < C_)             { w0 = qw[ch*3]; w1 = qw[ch*3+1]; w2 = qw[ch*3+2]; bias = qb[ch]; }
    else if (ch < C_ + HD_)  { int cc = ch - C_;       w0 = kw[cc*3]; w1 = kw[cc*3+1]; w2 = kw[cc*3+2]; bias = kbias[cc]; }
    else                     { int cc = ch - C_ - HD_; w0 = vw[cc*3]; w1 = vw[cc*3+1]; w2 = vw[cc*3+2]; bias = vbias[cc]; }
    float y = fmaf(x0, w0, fmaf(x1, w1, fmaf(x2, w2, bias)));
    if (ch < C_) {
        int h = ch >> 6, d = ch & 63;
        Qs[(((size_t)b * H_ + h) * T_ + t) * HD_ + d] = f2bf(y * 0.125f);
    } else if (ch < C_ + HD_) {
        Kb[((size_t)b * T_ + t) * HD_ + (ch - C_)] = f2bf(y);
    } else {
        Vt[((size_t)b * HD_ + (ch - C_ - HD_)) * T_ + t] = f2bf(y);
    }
}

// Flash-style causal MQA, v3 (m214-style swapped QK^T, 32x32x16 MFMA).
// 4 independent waves/block, each owns 32 q-rows (qt balanced-paired so every
// block has equal triangular work). Per KV-64 tile:
//   S^T = mfma(K_tile, Q)  -> lane holds one q-row's scores in-lane
//   softmax: 31 in-lane ops + ONE shfl_xor(32); no 16-lane trees, no LDS
//   P -> bf16 B-frags via v_cvt_pk + lane^32 exchange (T12 recipe)
//   O^T += mfma(Vt_frag, P_frag); V pre-transposed (B,64,T)
// C/D layout (m74-verified): col=lane&31, row=(reg&3)+8*(reg>>2)+4*(lane>>5).
__global__ __launch_bounds__(256) void attn_kernel(const short* __restrict__ Qs,
        const short* __restrict__ Kb, const short* __restrict__ Vt,
        short* __restrict__ Y) {
    int bh = blockIdx.y;
    int b = bh >> 4;
    int h = bh & 15;
    int wid = threadIdx.x >> 6, l = threadIdx.x & 63;
    int ql = l & 31, hi = l >> 5;
    int k2 = blockIdx.x;                       // 0..15
    int qt = (wid < 2) ? (2 * k2 + wid) : (63 - 2 * k2 - (wid & 1));
    int qbase = qt * 32;
    int qi = qbase + ql;

    // Q B-fragments, 4 contraction steps of 16 over HD=64 (col=q=ql, d=hi*8+j)
    const short* Qp = Qs + ((size_t)bh * T_ + qi) * HD_ + hi * 8;
    bf16x8 qf[4];
    #pragma unroll
    for (int s = 0; s < 4; s++) qf[s] = *(const bf16x8*)(Qp + s * 16);

    f32x16 Oa0 = {}, Oa1 = {};                 // O^T, d-blocks [0,32) and [32,64)
    float mrow = -1e30f, lsum = 0.f;

    const short* Kbase = Kb + (size_t)b * T_ * HD_;
    const short* Vbase = Vt + (size_t)b * HD_ * T_;

    int nt = (qt >> 1) + 1;
    for (int it = 0; it < nt; it++) {
        int kt0 = it * 64;
        // ---- S^T: two 32-row k-subtiles, contraction over d ----
        f32x16 sv0 = {}, sv1 = {};
        #pragma unroll
        for (int s = 0; s < 4; s++) {
            bf16x8 ka = *(const bf16x8*)(Kbase + (size_t)(kt0 + ql) * HD_ + s * 16 + hi * 8);
            sv0 = __builtin_amdgcn_mfma_f32_32x32x16_bf16(ka, qf[s], sv0, 0, 0, 0);
        }
        #pragma unroll
        for (int s = 0; s < 4; s++) {
            bf16x8 ka = *(const bf16x8*)(Kbase + (size_t)(kt0 + 32 + ql) * HD_ + s * 16 + hi * 8);
            sv1 = __builtin_amdgcn_mfma_f32_32x32x16_bf16(ka, qf[s], sv1, 0, 0, 0);
        }
        // ---- causal mask (last tile only; scale folded into Q) ----
        if (kt0 + 64 > qbase) {
            #pragma unroll
            for (int r = 0; r < 16; r++) {
                int kl = (r & 3) + 8 * (r >> 2) + 4 * hi;
                if (kt0 + kl > qi)      sv0[r] = -1e30f;
                if (kt0 + 32 + kl > qi) sv1[r] = -1e30f;
            }
        }
        // ---- online softmax: in-lane + one lane^32 exchange ----
        float pmax = sv0[0];
        #pragma unroll
        for (int r = 1; r < 16; r++) pmax = fmaxf(pmax, sv0[r]);
        #pragma unroll
        for (int r = 0; r < 16; r++) pmax = fmaxf(pmax, sv1[r]);
        pmax = fmaxf(pmax, __shfl_xor(pmax, 32, 64));
        float nm = fmaxf(mrow, pmax);
        float alpha = __expf(mrow - nm);
        mrow = nm;
        float psum = 0.f;
        #pragma unroll
        for (int r = 0; r < 16; r++) { sv0[r] = __expf(sv0[r] - nm); psum += sv0[r]; }
        #pragma unroll
        for (int r = 0; r < 16; r++) { sv1[r] = __expf(sv1[r] - nm); psum += sv1[r]; }
        psum += __shfl_xor(psum, 32, 64);
        lsum = lsum * alpha + psum;
        #pragma unroll
        for (int r = 0; r < 16; r++) { Oa0[r] *= alpha; Oa1[r] *= alpha; }
        // ---- P redistribution (cvt_pk + lane^32) + PV ----
        #pragma unroll
        for (int sub = 0; sub < 2; sub++) {
            #pragma unroll
            for (int hh = 0; hh < 2; hh++) {
                // X0..X3 pack this lane's 8 k-values (regs hh*8..hh*8+7)
                unsigned X0, X1, X2, X3;
                if (sub == 0) {
                    X0 = cvtpk(sv0[hh * 8 + 0], sv0[hh * 8 + 1]);
                    X1 = cvtpk(sv0[hh * 8 + 2], sv0[hh * 8 + 3]);
                    X2 = cvtpk(sv0[hh * 8 + 4], sv0[hh * 8 + 5]);
                    X3 = cvtpk(sv0[hh * 8 + 6], sv0[hh * 8 + 7]);
                } else {
                    X0 = cvtpk(sv1[hh * 8 + 0], sv1[hh * 8 + 1]);
                    X1 = cvtpk(sv1[hh * 8 + 2], sv1[hh * 8 + 3]);
                    X2 = cvtpk(sv1[hh * 8 + 4], sv1[hh * 8 + 5]);
                    X3 = cvtpk(sv1[hh * 8 + 6], sv1[hh * 8 + 7]);
                }
                unsigned sX0 = __shfl_xor(X0, 32, 64);
                unsigned sX1 = __shfl_xor(X1, 32, 64);
                unsigned sX2 = __shfl_xor(X2, 32, 64);
                unsigned sX3 = __shfl_xor(X3, 32, 64);
                union { u32x4 u; bf16x8 v; } pw;
                pw.u[0] = hi ? sX2 : X0;   // k elems (hi*8 + 0,1)
                pw.u[1] = hi ? sX3 : X1;   // k elems (hi*8 + 2,3)
                pw.u[2] = hi ? X2 : sX0;   // k elems (hi*8 + 4,5)
                pw.u[3] = hi ? X3 : sX1;   // k elems (hi*8 + 6,7)
                int koff = kt0 + sub * 32 + hh * 16 + hi * 8;
                bf16x8 va0 = *(const bf16x8*)(Vbase + (size_t)ql * T_ + koff);
                bf16x8 va1 = *(const bf16x8*)(Vbase + (size_t)(32 + ql) * T_ + koff);
                Oa0 = __builtin_amdgcn_mfma_f32_32x32x16_bf16(va0, pw.v, Oa0, 0, 0, 0);
                Oa1 = __builtin_amdgcn_mfma_f32_32x32x16_bf16(va1, pw.v, Oa1, 0, 0, 0);
            }
        }
    }
    // ---- epilogue: normalize, write one Y-row segment per lane ----
    float inv = 1.f / lsum;
    size_t orow = ((size_t)b * T_ + qi) * C_ + h * HD_;
    #pragma unroll
    for (int r = 0; r < 16; r += 2) {
        int d = (r & 3) + 8 * (r >> 2) + 4 * hi;       // r even -> d even; (r,r+1)->(d,d+1)
        *(unsigned*)(Y + orow + d)      = cvtpk(Oa0[r] * inv, Oa0[r + 1] * inv);
        *(unsigned*)(Y + orow + 32 + d) = cvtpk(Oa1[r] * inv, Oa1[r + 1] * inv);
    }
}

extern "C" void kernel_launch(void* const* d_in, const int* in_sizes, int n_in,
                              void* d_out, int out_size, void* d_ws, size_t ws_size,
                              hipStream_t stream) {
    const float* x     = (const float*)d_in[0];
    const float* Wqkv  = (const float*)d_in[1];
    const float* qw    = (const float*)d_in[2];
    const float* qb    = (const float*)d_in[3];
    const float* kw    = (const float*)d_in[4];
    const float* kbias = (const float*)d_in[5];
    const float* vw    = (const float*)d_in[6];
    const float* vbias = (const float*)d_in[7];
    const float* Wproj = (const float*)d_in[8];

    char* ws = (char*)d_ws;
    short* xb     = (short*)ws;                    //  8388608 B (reused as Ybf later)
    short* Wqkvb  = (short*)(ws + 8388608);        //  2359296 B
    short* Wprojb = (short*)(ws + 10747904);       //  2097152 B
    short* qkvb   = (short*)(ws + 12845056);       //  9437184 B
    short* Qsc    = (short*)(ws + 22282240);       //  8388608 B
    short* Kbf    = (short*)(ws + 30670848);       //   524288 B
    short* Vtr    = (short*)(ws + 31195136);       //   524288 B  (total 31.7 MB)
    short* Ybf    = xb;                            // x dead after gemm1

    const int M = B_ * T_;  // 4096

    // 0) f32 -> bf16: x, Wqkv, Wproj
    cvt_bf16<<<dim3(3136), 256, 0, stream>>>(x, Wqkv, Wproj, xb, Wqkvb, Wprojb);

    // 1) qkv = x @ Wqkv^T  (bf16 out)   grid 32*9 = 288 (%8==0)
    gemm_bt<true><<<dim3((M / 128) * (O_ / 128)), 256, 0, stream>>>(
        xb, Wqkvb, qkvb, M, O_, C_);

    // 2) causal dwconv + split + scale + V-transpose
    conv_split<<<dim3((B_ * T_ * O_) / 256), 256, 0, stream>>>(
        qkvb, qw, qb, kw, kbias, vw, vbias, Qsc, Kbf, Vtr);

    // 3) causal MQA attention -> y (B,T,C) bf16
    attn_kernel<<<dim3(16, B_ * H_), 256, 0, stream>>>(Qsc, Kbf, Vtr, Ybf);

    // 4) out = y @ Wproj^T -> f32 d_out   grid 32*8 = 256 (%8==0)
    gemm_bt<false><<<dim3((M / 128) * (C_ / 128)), 256, 0, stream>>>(
        Ybf, Wprojb, (float*)d_out, M, C_, C_);
}